// Round 16
// baseline (215.549 us; speedup 1.0000x reference)
//
#include <hip/hip_runtime.h>

#define TN 64
#define NB 2
#define CH 8
#define HH 128
#define WW 128
#define HW (HH*WW)        // 16384
#define CHW (CH*HW)       // 131072
#define NCHW (NB*CHW)     // 262144

// ---------------------------------------------------------------------------
// Pipeline (conv∘alpha = alpha∘conv, both linear, disjoint axes):
//   xT = transpose(x) as u8          [t*NB+n][c][h][w]   (x is binary spikes)
//   v1 = conv1(xT)                   f32 t-major
//   s1 = LIF1(alpha1(v1))  as u8
//   v2 = conv2(s1)                   f32 t-major
//   out = LIF2(alpha2(v2))           t-minor [n][c][h][w][t]
// ---------------------------------------------------------------------------

// K0: transpose x [n,c,h,w,t] f32(binary) -> xT [t*NB+n][c][h][w] u8.
__global__ __launch_bounds__(256) void k_tr(const float* __restrict__ x,
                                            unsigned char* __restrict__ xT) {
    __shared__ unsigned char lds[256 * 68];          // [e][68B] pad: 17 words/row
    const int tid = threadIdx.x;
    const size_t e0 = (size_t)blockIdx.x * 256;
    const float4* xb = reinterpret_cast<const float4*>(x + (e0 + tid) * TN);
    unsigned int* lds32 = reinterpret_cast<unsigned int*>(lds);
    #pragma unroll
    for (int k = 0; k < 16; ++k) {
        float4 v = xb[k];
        unsigned int p = ((unsigned)v.x) | (((unsigned)v.y) << 8) |
                         (((unsigned)v.z) << 16) | (((unsigned)v.w) << 24);
        lds32[tid * 17 + k] = p;                     // bank stride 17: conflict-free
    }
    __syncthreads();
    const int lane = tid & 63, w = tid >> 6;
    #pragma unroll
    for (int k = 0; k < 16; ++k) {
        int t = w * 16 + k;
        unsigned int b0 = lds[(4 * lane + 0) * 68 + t];
        unsigned int b1 = lds[(4 * lane + 1) * 68 + t];
        unsigned int b2 = lds[(4 * lane + 2) * 68 + t];
        unsigned int b3 = lds[(4 * lane + 3) * 68 + t];
        unsigned int p = b0 | (b1 << 8) | (b2 << 16) | (b3 << 24);
        *reinterpret_cast<unsigned int*>(xT + (size_t)t * NCHW + e0 + 4 * lane) = p;
    }
}

// ---------------------------------------------------------------------------
// K1: conv1 5x5 pad=2 on u8, TWO images per block (amortizes weight s_loads,
// goff math, staging addressing 2x -> 8 FMA per weight value).
// LDS 2 x [8][12][136] u8 = 26.1 KB, one barrier. acc 2x[8][4] = 64 VGPR.
// ---------------------------------------------------------------------------
__global__ __launch_bounds__(256, 4) void k_conv1(const unsigned char* __restrict__ in,
                                                  const float* __restrict__ w1,
                                                  float* __restrict__ outp) {
    __shared__ __align__(16) unsigned char lds8[2][CH * 12 * 136];  // 2x13056 B
    const int img0 = blockIdx.y * 2;            // image pair
    const int h0 = blockIdx.x * 8;              // 16 y-tiles
    const int tid = threadIdx.x;
    const int yi = tid >> 5;                    // 0..7
    const int x0 = (tid & 31) * 4;              // 0..124
    const unsigned char* base0 = in + (size_t)img0 * CHW;
    const unsigned char* base1 = base0 + CHW;

    int goff[7];                                // 12*136 = 1632 slots/channel
    #pragma unroll
    for (int k = 0; k < 7; ++k) {
        int idx = tid + (k << 8);
        int r = idx / 136;
        int c = idx - r * 136;
        int gh = h0 + r - 2, gw = c - 2;
        bool ok = (idx < 1632) && (gh >= 0) && (gh < HH) && (gw >= 0) && (gw < WW);
        goff[k] = ok ? (gh * WW + gw) : -1;
    }

    #pragma unroll
    for (int ci = 0; ci < CH; ++ci) {
        const unsigned char* cb0 = base0 + ci * HW;
        const unsigned char* cb1 = base1 + ci * HW;
        #pragma unroll
        for (int k = 0; k < 7; ++k) {
            int idx = tid + (k << 8);
            if (k < 6 || idx < 1632) {
                int g = goff[k];
                int gc = g < 0 ? 0 : g;
                unsigned char v0 = cb0[gc];
                unsigned char v1 = cb1[gc];
                lds8[0][ci * 1632 + idx] = (g < 0) ? (unsigned char)0 : v0;
                lds8[1][ci * 1632 + idx] = (g < 0) ? (unsigned char)0 : v1;
            }
        }
    }
    __syncthreads();                            // the ONLY barrier

    float acc0[CH][4], acc1[CH][4];
    #pragma unroll
    for (int co = 0; co < CH; ++co)
        #pragma unroll
        for (int xo = 0; xo < 4; ++xo) { acc0[co][xo] = 0.f; acc1[co][xo] = 0.f; }

    for (int ci = 0; ci < CH; ++ci) {
        const unsigned char* cp0 = lds8[0] + ci * 1632;
        const unsigned char* cp1 = lds8[1] + ci * 1632;
        #pragma unroll
        for (int ky = 0; ky < 5; ++ky) {
            const unsigned int* p0 =
                reinterpret_cast<const unsigned int*>(cp0 + (yi + ky) * 136 + x0);
            const unsigned int* p1 =
                reinterpret_cast<const unsigned int*>(cp1 + (yi + ky) * 136 + x0);
            unsigned int a0 = p0[0], b0 = p0[1];
            unsigned int a1 = p1[0], b1 = p1[1];
            float f0[8] = {(float)(a0 & 0xff), (float)((a0 >> 8) & 0xff),
                           (float)((a0 >> 16) & 0xff), (float)(a0 >> 24),
                           (float)(b0 & 0xff), (float)((b0 >> 8) & 0xff),
                           (float)((b0 >> 16) & 0xff), (float)(b0 >> 24)};
            float f1[8] = {(float)(a1 & 0xff), (float)((a1 >> 8) & 0xff),
                           (float)((a1 >> 16) & 0xff), (float)(a1 >> 24),
                           (float)(b1 & 0xff), (float)((b1 >> 8) & 0xff),
                           (float)((b1 >> 16) & 0xff), (float)(b1 >> 24)};
            #pragma unroll
            for (int co = 0; co < CH; ++co) {
                const float* wp = w1 + (co * CH + ci) * 25 + ky * 5;
                #pragma unroll
                for (int kx = 0; kx < 5; ++kx) {
                    float wv = wp[kx];
                    #pragma unroll
                    for (int xo = 0; xo < 4; ++xo) {
                        acc0[co][xo] = fmaf(wv, f0[kx + xo], acc0[co][xo]);
                        acc1[co][xo] = fmaf(wv, f1[kx + xo], acc1[co][xo]);
                    }
                }
            }
        }
    }

    float* ob0 = outp + (size_t)img0 * CHW + (h0 + yi) * WW + x0;
    float* ob1 = ob0 + CHW;
    #pragma unroll
    for (int co = 0; co < CH; ++co) {
        *reinterpret_cast<float4*>(ob0 + co * HW) =
            make_float4(acc0[co][0], acc0[co][1], acc0[co][2], acc0[co][3]);
        *reinterpret_cast<float4*>(ob1 + co * HW) =
            make_float4(acc1[co][0], acc1[co][1], acc1[co][2], acc1[co][3]);
    }
}

// ---------------------------------------------------------------------------
// K2: fused alpha1 (tau=1) + LIF1 (theta=30, tauRef=1) -> s1 u8.
// ---------------------------------------------------------------------------
__global__ __launch_bounds__(256) void k_alif1(const float* __restrict__ v1,
                                               unsigned char* __restrict__ s1) {
    int e2 = blockIdx.x * blockDim.x + threadIdx.x;   // 0..NCHW/2-1
    if (e2 >= NCHW / 2) return;
    const float d1 = 0.36787944117144233f;  // exp(-1)
    const float c1 = 2.7182818284590452f;   // e
    const float dr = 0.36787944117144233f;  // exp(-1)
    const float rg = 81.54845485377136f;    // 30*e
    const float th = 30.f;
    float P0 = 0.f, Q0 = 0.f, Pr0 = 0.f, Qr0 = 0.f;
    float P1 = 0.f, Q1 = 0.f, Pr1 = 0.f, Qr1 = 0.f;
    const float2* ve = reinterpret_cast<const float2*>(v1);
    #pragma unroll 8
    for (int t = 0; t < TN; ++t) {
        float2 v = ve[(size_t)t * (NCHW / 2) + e2];
        Q0 = d1 * (Q0 + P0); P0 = d1 * P0 + v.x;
        Qr0 = dr * (Qr0 + Pr0);
        float s0 = (c1 * Q0 - rg * Qr0 >= th) ? 1.0f : 0.0f;
        Pr0 = dr * Pr0 + s0;
        Q1 = d1 * (Q1 + P1); P1 = d1 * P1 + v.y;
        Qr1 = dr * (Qr1 + Pr1);
        float s1v = (c1 * Q1 - rg * Qr1 >= th) ? 1.0f : 0.0f;
        Pr1 = dr * Pr1 + s1v;
        uchar2 o; o.x = (unsigned char)s0; o.y = (unsigned char)s1v;
        *reinterpret_cast<uchar2*>(s1 + (size_t)t * NCHW + 2 * e2) = o;
    }
}

// ---------------------------------------------------------------------------
// K3: conv2 3x3 pad=1 on u8 spikes, two images per block.
// LDS 2 x [8][10][136] u8 = 21.8 KB.
// ---------------------------------------------------------------------------
__global__ __launch_bounds__(256, 4) void k_conv2(const unsigned char* __restrict__ in,
                                                  const float* __restrict__ w2,
                                                  float* __restrict__ outp) {
    __shared__ __align__(16) unsigned char lds8[2][CH * 10 * 136];  // 2x10880 B
    const int img0 = blockIdx.y * 2;
    const int h0 = blockIdx.x * 8;
    const int tid = threadIdx.x;
    const int yi = tid >> 5;
    const int x0 = (tid & 31) * 4;
    const unsigned char* base0 = in + (size_t)img0 * CHW;
    const unsigned char* base1 = base0 + CHW;

    int goff[6];                                // 10*136 = 1360 slots/channel
    #pragma unroll
    for (int k = 0; k < 6; ++k) {
        int idx = tid + (k << 8);
        int r = idx / 136;
        int c = idx - r * 136;
        int gh = h0 + r - 1, gw = c - 1;
        bool ok = (idx < 1360) && (gh >= 0) && (gh < HH) && (gw >= 0) && (gw < WW);
        goff[k] = ok ? (gh * WW + gw) : -1;
    }

    #pragma unroll
    for (int ci = 0; ci < CH; ++ci) {
        const unsigned char* cb0 = base0 + ci * HW;
        const unsigned char* cb1 = base1 + ci * HW;
        #pragma unroll
        for (int k = 0; k < 6; ++k) {
            int idx = tid + (k << 8);
            if (k < 5 || idx < 1360) {
                int g = goff[k];
                int gc = g < 0 ? 0 : g;
                unsigned char v0 = cb0[gc];
                unsigned char v1 = cb1[gc];
                lds8[0][ci * 1360 + idx] = (g < 0) ? (unsigned char)0 : v0;
                lds8[1][ci * 1360 + idx] = (g < 0) ? (unsigned char)0 : v1;
            }
        }
    }
    __syncthreads();                            // the ONLY barrier

    float acc0[CH][4], acc1[CH][4];
    #pragma unroll
    for (int co = 0; co < CH; ++co)
        #pragma unroll
        for (int xo = 0; xo < 4; ++xo) { acc0[co][xo] = 0.f; acc1[co][xo] = 0.f; }

    for (int ci = 0; ci < CH; ++ci) {
        const unsigned char* cp0 = lds8[0] + ci * 1360;
        const unsigned char* cp1 = lds8[1] + ci * 1360;
        #pragma unroll
        for (int ky = 0; ky < 3; ++ky) {
            const unsigned int* p0 =
                reinterpret_cast<const unsigned int*>(cp0 + (yi + ky) * 136 + x0);
            const unsigned int* p1 =
                reinterpret_cast<const unsigned int*>(cp1 + (yi + ky) * 136 + x0);
            unsigned int a0 = p0[0], b0 = p0[1];
            unsigned int a1 = p1[0], b1 = p1[1];
            float f0[8] = {(float)(a0 & 0xff), (float)((a0 >> 8) & 0xff),
                           (float)((a0 >> 16) & 0xff), (float)(a0 >> 24),
                           (float)(b0 & 0xff), (float)((b0 >> 8) & 0xff),
                           (float)((b0 >> 16) & 0xff), (float)(b0 >> 24)};
            float f1[8] = {(float)(a1 & 0xff), (float)((a1 >> 8) & 0xff),
                           (float)((a1 >> 16) & 0xff), (float)(a1 >> 24),
                           (float)(b1 & 0xff), (float)((b1 >> 8) & 0xff),
                           (float)((b1 >> 16) & 0xff), (float)(b1 >> 24)};
            #pragma unroll
            for (int co = 0; co < CH; ++co) {
                const float* wp = w2 + (co * CH + ci) * 9 + ky * 3;
                #pragma unroll
                for (int kx = 0; kx < 3; ++kx) {
                    float wv = wp[kx];
                    #pragma unroll
                    for (int xo = 0; xo < 4; ++xo) {
                        acc0[co][xo] = fmaf(wv, f0[kx + xo], acc0[co][xo]);
                        acc1[co][xo] = fmaf(wv, f1[kx + xo], acc1[co][xo]);
                    }
                }
            }
        }
    }

    float* ob0 = outp + (size_t)img0 * CHW + (h0 + yi) * WW + x0;
    float* ob1 = ob0 + CHW;
    #pragma unroll
    for (int co = 0; co < CH; ++co) {
        *reinterpret_cast<float4*>(ob0 + co * HW) =
            make_float4(acc0[co][0], acc0[co][1], acc0[co][2], acc0[co][3]);
        *reinterpret_cast<float4*>(ob1 + co * HW) =
            make_float4(acc1[co][0], acc1[co][1], acc1[co][2], acc1[co][3]);
    }
}

// ---------------------------------------------------------------------------
// K4: fused alpha2 (tau=2) + LIF2 (theta=50, tauRef=2), t-minor f32 output.
// ---------------------------------------------------------------------------
__global__ __launch_bounds__(256) void k_alif2(const float* __restrict__ v2,
                                               float* __restrict__ outp) {
    int e = blockIdx.x * blockDim.x + threadIdx.x;
    if (e >= NCHW) return;
    const float d2 = 0.60653065971263342f;  // exp(-0.5)
    const float c2 = 1.35914091422952262f;  // e/2
    const float dr = 0.60653065971263342f;  // exp(-0.5)
    const float rg = 67.95704571147613f;    // 25*e
    const float th = 50.f;
    float P = 0.f, Q = 0.f, Pr = 0.f, Qr = 0.f;
    float sv[TN];
    #pragma unroll
    for (int t = 0; t < TN; ++t) {
        Q = d2 * (Q + P);
        P = d2 * P + v2[(size_t)t * NCHW + e];
        Qr = dr * (Qr + Pr);
        float s = (c2 * Q - rg * Qr >= th) ? 1.0f : 0.0f;
        Pr = dr * Pr + s;
        sv[t] = s;
    }
    float4* o = reinterpret_cast<float4*>(outp + (size_t)e * TN);
    #pragma unroll
    for (int i = 0; i < TN / 4; ++i)
        o[i] = make_float4(sv[4 * i], sv[4 * i + 1], sv[4 * i + 2], sv[4 * i + 3]);
}

// ---------------------------------------------------------------------------
extern "C" void kernel_launch(void* const* d_in, const int* in_sizes, int n_in,
                              void* d_out, int out_size, void* d_ws, size_t ws_size,
                              hipStream_t stream) {
    const float* x  = (const float*)d_in[0];   // [2,8,128,128,64] binary
    const float* w1 = (const float*)d_in[1];   // [8,8,5,5]
    const float* w2 = (const float*)d_in[2];   // [8,8,3,3]
    float* out = (float*)d_out;                // [2,8,128,128,64]

    // workspace: v-buffer f32 64MB (v1 then v2) + xT u8 16MB + s1 u8 16MB
    float* vbuf = (float*)d_ws;
    unsigned char* xT = (unsigned char*)d_ws + (size_t)TN * NCHW * 4;
    unsigned char* s1 = xT + (size_t)TN * NCHW;

    dim3 blk(256);
    dim3 grd_pt(NCHW / 256);          // 1024 blocks
    dim3 grd_pt2(NCHW / 512);         // 512 blocks (float2 kernel)
    dim3 grd_cv(16, TN * NB / 2);     // 16 row-tiles x 64 image-pairs

    k_tr<<<grd_pt, blk, 0, stream>>>(x, xT);
    k_conv1<<<grd_cv, blk, 0, stream>>>(xT, w1, vbuf);
    k_alif1<<<grd_pt2, blk, 0, stream>>>(vbuf, s1);
    k_conv2<<<grd_cv, blk, 0, stream>>>(s1, w2, vbuf);
    k_alif2<<<grd_pt, blk, 0, stream>>>(vbuf, out);
}

// Round 17
// 193.464 us; speedup vs baseline: 1.1142x; 1.1142x over previous
//
#include <hip/hip_runtime.h>

#define TN 64
#define NB 2
#define CH 8
#define HH 128
#define WW 128
#define HW (HH*WW)        // 16384
#define CHW (CH*HW)       // 131072
#define NCHW (NB*CHW)     // 262144

// ---------------------------------------------------------------------------
// Pipeline (conv∘alpha = alpha∘conv, both linear, disjoint axes):
//   xT = transpose(x) as u8          [t*NB+n][c][h][w]   (x is binary spikes)
//   v1 = conv1(xT)                   f32 t-major
//   s1 = LIF1(alpha1(v1))  as u8
//   v2 = conv2(s1)                   f32 t-major
//   out = LIF2(alpha2(v2))           t-minor [n][c][h][w][t]
// ---------------------------------------------------------------------------

// K0: transpose x [n,c,h,w,t] f32(binary) -> xT [t*NB+n][c][h][w] u8.
__global__ __launch_bounds__(256) void k_tr(const float* __restrict__ x,
                                            unsigned char* __restrict__ xT) {
    __shared__ unsigned char lds[256 * 68];          // [e][68B] pad: 17 words/row
    const int tid = threadIdx.x;
    const size_t e0 = (size_t)blockIdx.x * 256;
    const float4* xb = reinterpret_cast<const float4*>(x + (e0 + tid) * TN);
    unsigned int* lds32 = reinterpret_cast<unsigned int*>(lds);
    #pragma unroll
    for (int k = 0; k < 16; ++k) {
        float4 v = xb[k];
        unsigned int p = ((unsigned)v.x) | (((unsigned)v.y) << 8) |
                         (((unsigned)v.z) << 16) | (((unsigned)v.w) << 24);
        lds32[tid * 17 + k] = p;                     // bank stride 17: conflict-free
    }
    __syncthreads();
    const int lane = tid & 63, w = tid >> 6;
    #pragma unroll
    for (int k = 0; k < 16; ++k) {
        int t = w * 16 + k;
        unsigned int b0 = lds[(4 * lane + 0) * 68 + t];
        unsigned int b1 = lds[(4 * lane + 1) * 68 + t];
        unsigned int b2 = lds[(4 * lane + 2) * 68 + t];
        unsigned int b3 = lds[(4 * lane + 3) * 68 + t];
        unsigned int p = b0 | (b1 << 8) | (b2 << 16) | (b3 << 24);
        *reinterpret_cast<unsigned int*>(xT + (size_t)t * NCHW + e0 + 4 * lane) = p;
    }
}

// ---------------------------------------------------------------------------
// K1: conv1 5x5 pad=2 on u8. One-barrier u8 tile, 8-px x-strips:
// 256 thr = 16 rows x 16 lanes x 8 px; LDS [8][20][136] u8 = 21.8 KB.
// Per (ci,ky): 3 ds_read_b32 + 12 cvt + 40 weight s_loads -> 320 FMAs
// (2x weight amortization vs R13 with no extra staging).
// ---------------------------------------------------------------------------
__global__ __launch_bounds__(256, 4) void k_conv1(const unsigned char* __restrict__ in,
                                                  const float* __restrict__ w1,
                                                  float* __restrict__ outp) {
    __shared__ __align__(16) unsigned char lds8[CH * 20 * 136];   // 21760 B
    const int img = blockIdx.y;                 // t*NB + n, 0..127
    const int h0 = blockIdx.x * 16;             // 8 y-tiles of 16 rows
    const int tid = threadIdx.x;
    const int yi = tid >> 4;                    // 0..15
    const int x0 = (tid & 15) * 8;              // 0..120
    const unsigned char* base = in + (size_t)img * CHW;

    // staging offsets: computed ONCE, reused for all 8 channels
    int goff[11];                               // 20*136 = 2720 slots/channel
    #pragma unroll
    for (int k = 0; k < 11; ++k) {
        int idx = tid + (k << 8);
        int r = idx / 136;
        int c = idx - r * 136;
        int gh = h0 + r - 2, gw = c - 2;
        bool ok = (idx < 2720) && (gh >= 0) && (gh < HH) && (gw >= 0) && (gw < WW);
        goff[k] = ok ? (gh * WW + gw) : -1;
    }

    #pragma unroll
    for (int ci = 0; ci < CH; ++ci) {
        const unsigned char* cb = base + ci * HW;
        #pragma unroll
        for (int k = 0; k < 11; ++k) {
            int idx = tid + (k << 8);
            if (k < 10 || idx < 2720) {
                int g = goff[k];
                int gc = g < 0 ? 0 : g;
                unsigned char v = cb[gc];
                lds8[ci * 2720 + idx] = (g < 0) ? (unsigned char)0 : v;
            }
        }
    }
    __syncthreads();                            // the ONLY barrier

    float acc[CH][8];
    #pragma unroll
    for (int co = 0; co < CH; ++co)
        #pragma unroll
        for (int xo = 0; xo < 8; ++xo) acc[co][xo] = 0.f;

    for (int ci = 0; ci < CH; ++ci) {
        const unsigned char* cp = lds8 + ci * 2720;
        #pragma unroll
        for (int ky = 0; ky < 5; ++ky) {
            const unsigned int* p =
                reinterpret_cast<const unsigned int*>(cp + (yi + ky) * 136 + x0);
            unsigned int a = p[0], b = p[1], c = p[2];
            float f[12] = {(float)(a & 0xff), (float)((a >> 8) & 0xff),
                           (float)((a >> 16) & 0xff), (float)(a >> 24),
                           (float)(b & 0xff), (float)((b >> 8) & 0xff),
                           (float)((b >> 16) & 0xff), (float)(b >> 24),
                           (float)(c & 0xff), (float)((c >> 8) & 0xff),
                           (float)((c >> 16) & 0xff), (float)(c >> 24)};
            #pragma unroll
            for (int co = 0; co < CH; ++co) {
                const float* wp = w1 + (co * CH + ci) * 25 + ky * 5;
                #pragma unroll
                for (int kx = 0; kx < 5; ++kx) {
                    float wv = wp[kx];
                    #pragma unroll
                    for (int xo = 0; xo < 8; ++xo)
                        acc[co][xo] = fmaf(wv, f[kx + xo], acc[co][xo]);
                }
            }
        }
    }

    float* ob = outp + (size_t)img * CHW + (h0 + yi) * WW + x0;
    #pragma unroll
    for (int co = 0; co < CH; ++co) {
        *reinterpret_cast<float4*>(ob + co * HW) =
            make_float4(acc[co][0], acc[co][1], acc[co][2], acc[co][3]);
        *reinterpret_cast<float4*>(ob + co * HW + 4) =
            make_float4(acc[co][4], acc[co][5], acc[co][6], acc[co][7]);
    }
}

// ---------------------------------------------------------------------------
// K2: fused alpha1 (tau=1) + LIF1 (theta=30, tauRef=1) -> s1 u8.
// ---------------------------------------------------------------------------
__global__ __launch_bounds__(256) void k_alif1(const float* __restrict__ v1,
                                               unsigned char* __restrict__ s1) {
    int e2 = blockIdx.x * blockDim.x + threadIdx.x;   // 0..NCHW/2-1
    if (e2 >= NCHW / 2) return;
    const float d1 = 0.36787944117144233f;  // exp(-1)
    const float c1 = 2.7182818284590452f;   // e
    const float dr = 0.36787944117144233f;  // exp(-1)
    const float rg = 81.54845485377136f;    // 30*e
    const float th = 30.f;
    float P0 = 0.f, Q0 = 0.f, Pr0 = 0.f, Qr0 = 0.f;
    float P1 = 0.f, Q1 = 0.f, Pr1 = 0.f, Qr1 = 0.f;
    const float2* ve = reinterpret_cast<const float2*>(v1);
    #pragma unroll 8
    for (int t = 0; t < TN; ++t) {
        float2 v = ve[(size_t)t * (NCHW / 2) + e2];
        Q0 = d1 * (Q0 + P0); P0 = d1 * P0 + v.x;
        Qr0 = dr * (Qr0 + Pr0);
        float s0 = (c1 * Q0 - rg * Qr0 >= th) ? 1.0f : 0.0f;
        Pr0 = dr * Pr0 + s0;
        Q1 = d1 * (Q1 + P1); P1 = d1 * P1 + v.y;
        Qr1 = dr * (Qr1 + Pr1);
        float s1v = (c1 * Q1 - rg * Qr1 >= th) ? 1.0f : 0.0f;
        Pr1 = dr * Pr1 + s1v;
        uchar2 o; o.x = (unsigned char)s0; o.y = (unsigned char)s1v;
        *reinterpret_cast<uchar2*>(s1 + (size_t)t * NCHW + 2 * e2) = o;
    }
}

// ---------------------------------------------------------------------------
// K3: conv2 3x3 pad=1 on u8 spikes. Same 8-px strip structure.
// LDS [8][18][136] u8 = 19.6 KB.
// ---------------------------------------------------------------------------
__global__ __launch_bounds__(256, 4) void k_conv2(const unsigned char* __restrict__ in,
                                                  const float* __restrict__ w2,
                                                  float* __restrict__ outp) {
    __shared__ __align__(16) unsigned char lds8[CH * 18 * 136];   // 19584 B
    const int img = blockIdx.y;
    const int h0 = blockIdx.x * 16;
    const int tid = threadIdx.x;
    const int yi = tid >> 4;                    // 0..15
    const int x0 = (tid & 15) * 8;              // 0..120
    const unsigned char* base = in + (size_t)img * CHW;

    int goff[10];                               // 18*136 = 2448 slots/channel
    #pragma unroll
    for (int k = 0; k < 10; ++k) {
        int idx = tid + (k << 8);
        int r = idx / 136;
        int c = idx - r * 136;
        int gh = h0 + r - 1, gw = c - 1;
        bool ok = (idx < 2448) && (gh >= 0) && (gh < HH) && (gw >= 0) && (gw < WW);
        goff[k] = ok ? (gh * WW + gw) : -1;
    }

    #pragma unroll
    for (int ci = 0; ci < CH; ++ci) {
        const unsigned char* cb = base + ci * HW;
        #pragma unroll
        for (int k = 0; k < 10; ++k) {
            int idx = tid + (k << 8);
            if (k < 9 || idx < 2448) {
                int g = goff[k];
                int gc = g < 0 ? 0 : g;
                unsigned char v = cb[gc];
                lds8[ci * 2448 + idx] = (g < 0) ? (unsigned char)0 : v;
            }
        }
    }
    __syncthreads();                            // the ONLY barrier

    float acc[CH][8];
    #pragma unroll
    for (int co = 0; co < CH; ++co)
        #pragma unroll
        for (int xo = 0; xo < 8; ++xo) acc[co][xo] = 0.f;

    for (int ci = 0; ci < CH; ++ci) {
        const unsigned char* cp = lds8 + ci * 2448;
        #pragma unroll
        for (int ky = 0; ky < 3; ++ky) {
            const unsigned int* p =
                reinterpret_cast<const unsigned int*>(cp + (yi + ky) * 136 + x0);
            unsigned int a = p[0], b = p[1], c = p[2];
            float f[12] = {(float)(a & 0xff), (float)((a >> 8) & 0xff),
                           (float)((a >> 16) & 0xff), (float)(a >> 24),
                           (float)(b & 0xff), (float)((b >> 8) & 0xff),
                           (float)((b >> 16) & 0xff), (float)(b >> 24),
                           (float)(c & 0xff), (float)((c >> 8) & 0xff),
                           (float)((c >> 16) & 0xff), (float)(c >> 24)};
            #pragma unroll
            for (int co = 0; co < CH; ++co) {
                const float* wp = w2 + (co * CH + ci) * 9 + ky * 3;
                #pragma unroll
                for (int kx = 0; kx < 3; ++kx) {
                    float wv = wp[kx];
                    #pragma unroll
                    for (int xo = 0; xo < 8; ++xo)
                        acc[co][xo] = fmaf(wv, f[kx + xo], acc[co][xo]);
                }
            }
        }
    }

    float* ob = outp + (size_t)img * CHW + (h0 + yi) * WW + x0;
    #pragma unroll
    for (int co = 0; co < CH; ++co) {
        *reinterpret_cast<float4*>(ob + co * HW) =
            make_float4(acc[co][0], acc[co][1], acc[co][2], acc[co][3]);
        *reinterpret_cast<float4*>(ob + co * HW + 4) =
            make_float4(acc[co][4], acc[co][5], acc[co][6], acc[co][7]);
    }
}

// ---------------------------------------------------------------------------
// K4: fused alpha2 (tau=2) + LIF2 (theta=50, tauRef=2), t-minor f32 output.
// ---------------------------------------------------------------------------
__global__ __launch_bounds__(256) void k_alif2(const float* __restrict__ v2,
                                               float* __restrict__ outp) {
    int e = blockIdx.x * blockDim.x + threadIdx.x;
    if (e >= NCHW) return;
    const float d2 = 0.60653065971263342f;  // exp(-0.5)
    const float c2 = 1.35914091422952262f;  // e/2
    const float dr = 0.60653065971263342f;  // exp(-0.5)
    const float rg = 67.95704571147613f;    // 25*e
    const float th = 50.f;
    float P = 0.f, Q = 0.f, Pr = 0.f, Qr = 0.f;
    float sv[TN];
    #pragma unroll
    for (int t = 0; t < TN; ++t) {
        Q = d2 * (Q + P);
        P = d2 * P + v2[(size_t)t * NCHW + e];
        Qr = dr * (Qr + Pr);
        float s = (c2 * Q - rg * Qr >= th) ? 1.0f : 0.0f;
        Pr = dr * Pr + s;
        sv[t] = s;
    }
    float4* o = reinterpret_cast<float4*>(outp + (size_t)e * TN);
    #pragma unroll
    for (int i = 0; i < TN / 4; ++i)
        o[i] = make_float4(sv[4 * i], sv[4 * i + 1], sv[4 * i + 2], sv[4 * i + 3]);
}

// ---------------------------------------------------------------------------
extern "C" void kernel_launch(void* const* d_in, const int* in_sizes, int n_in,
                              void* d_out, int out_size, void* d_ws, size_t ws_size,
                              hipStream_t stream) {
    const float* x  = (const float*)d_in[0];   // [2,8,128,128,64] binary
    const float* w1 = (const float*)d_in[1];   // [8,8,5,5]
    const float* w2 = (const float*)d_in[2];   // [8,8,3,3]
    float* out = (float*)d_out;                // [2,8,128,128,64]

    // workspace: v-buffer f32 64MB (v1 then v2) + xT u8 16MB + s1 u8 16MB
    float* vbuf = (float*)d_ws;
    unsigned char* xT = (unsigned char*)d_ws + (size_t)TN * NCHW * 4;
    unsigned char* s1 = xT + (size_t)TN * NCHW;

    dim3 blk(256);
    dim3 grd_pt(NCHW / 256);          // 1024 blocks
    dim3 grd_pt2(NCHW / 512);         // 512 blocks (float2 kernel)
    dim3 grd_cv(8, TN * NB);          // 8 row-tiles (16 rows) x 128 images

    k_tr<<<grd_pt, blk, 0, stream>>>(x, xT);
    k_conv1<<<grd_cv, blk, 0, stream>>>(xT, w1, vbuf);
    k_alif1<<<grd_pt2, blk, 0, stream>>>(vbuf, s1);
    k_conv2<<<grd_cv, blk, 0, stream>>>(s1, w2, vbuf);
    k_alif2<<<grd_pt, blk, 0, stream>>>(vbuf, out);
}

// Round 18
// 181.530 us; speedup vs baseline: 1.1874x; 1.0657x over previous
//
#include <hip/hip_runtime.h>

#define TN 64
#define NB 2
#define CH 8
#define HH 128
#define WW 128
#define HW (HH*WW)        // 16384
#define CHW (CH*HW)       // 131072
#define NCHW (NB*CHW)     // 262144

// ---------------------------------------------------------------------------
// Pipeline (conv∘alpha = alpha∘conv, both linear, disjoint axes):
//   xT = transpose(x) as u8          [t*NB+n][c][h][w]   (x is binary spikes)
//   v1 = conv1(xT)                   f32 t-major
//   s1 = LIF1(alpha1(v1))  as u8
//   v2 = conv2(s1)                   f32 t-major
//   out = LIF2(alpha2(v2))           t-minor [n][c][h][w][t]
// ---------------------------------------------------------------------------

// K0: transpose x [n,c,h,w,t] f32(binary) -> xT [t*NB+n][c][h][w] u8.
__global__ __launch_bounds__(256) void k_tr(const float* __restrict__ x,
                                            unsigned char* __restrict__ xT) {
    __shared__ unsigned char lds[256 * 68];          // [e][68B] pad: 17 words/row
    const int tid = threadIdx.x;
    const size_t e0 = (size_t)blockIdx.x * 256;
    const float4* xb = reinterpret_cast<const float4*>(x + (e0 + tid) * TN);
    unsigned int* lds32 = reinterpret_cast<unsigned int*>(lds);
    #pragma unroll
    for (int k = 0; k < 16; ++k) {
        float4 v = xb[k];
        unsigned int p = ((unsigned)v.x) | (((unsigned)v.y) << 8) |
                         (((unsigned)v.z) << 16) | (((unsigned)v.w) << 24);
        lds32[tid * 17 + k] = p;                     // bank stride 17: conflict-free
    }
    __syncthreads();
    const int lane = tid & 63, w = tid >> 6;
    #pragma unroll
    for (int k = 0; k < 16; ++k) {
        int t = w * 16 + k;
        unsigned int b0 = lds[(4 * lane + 0) * 68 + t];
        unsigned int b1 = lds[(4 * lane + 1) * 68 + t];
        unsigned int b2 = lds[(4 * lane + 2) * 68 + t];
        unsigned int b3 = lds[(4 * lane + 3) * 68 + t];
        unsigned int p = b0 | (b1 << 8) | (b2 << 16) | (b3 << 24);
        *reinterpret_cast<unsigned int*>(xT + (size_t)t * NCHW + e0 + 4 * lane) = p;
    }
}

// ---------------------------------------------------------------------------
// K1: conv1 5x5 pad=2 on u8 input (R13 structure, + s_setprio around FMA).
// WHOLE 8-channel u8 tile in LDS ([8][12][136] = 13.1 KB) staged once ->
// ONE barrier; 6400-FMA loop runs sync-free. u8->f32 on read (v_cvt).
// ---------------------------------------------------------------------------
__global__ __launch_bounds__(256, 4) void k_conv1(const unsigned char* __restrict__ in,
                                                  const float* __restrict__ w1,
                                                  float* __restrict__ outp) {
    __shared__ __align__(16) unsigned char lds8[CH * 12 * 136];   // 13056 B
    const int img = blockIdx.y;                 // t*NB + n, 0..127
    const int h0 = blockIdx.x * 8;              // 16 y-tiles
    const int tid = threadIdx.x;
    const int yi = tid >> 5;                    // 0..7
    const int x0 = (tid & 31) * 4;              // 0..124
    const unsigned char* base = in + (size_t)img * CHW;

    // staging offsets: computed ONCE, reused for all 8 channels
    int goff[7];                                // 12*136 = 1632 slots/channel
    #pragma unroll
    for (int k = 0; k < 7; ++k) {
        int idx = tid + (k << 8);
        int r = idx / 136;
        int c = idx - r * 136;
        int gh = h0 + r - 2, gw = c - 2;
        bool ok = (idx < 1632) && (gh >= 0) && (gh < HH) && (gw >= 0) && (gw < WW);
        goff[k] = ok ? (gh * WW + gw) : -1;
    }

    #pragma unroll
    for (int ci = 0; ci < CH; ++ci) {
        const unsigned char* cb = base + ci * HW;
        #pragma unroll
        for (int k = 0; k < 7; ++k) {
            int idx = tid + (k << 8);
            if (k < 6 || idx < 1632) {
                int g = goff[k];
                int gc = g < 0 ? 0 : g;
                unsigned char v = cb[gc];
                lds8[ci * 1632 + idx] = (g < 0) ? (unsigned char)0 : v;
            }
        }
    }
    __syncthreads();                            // the ONLY barrier

    float acc[CH][4];
    #pragma unroll
    for (int co = 0; co < CH; ++co)
        #pragma unroll
        for (int xo = 0; xo < 4; ++xo) acc[co][xo] = 0.f;

    __builtin_amdgcn_s_setprio(1);              // T5: favor FMA-phase waves
    for (int ci = 0; ci < CH; ++ci) {
        const unsigned char* cp = lds8 + ci * 1632;
        #pragma unroll
        for (int ky = 0; ky < 5; ++ky) {
            const unsigned int* p =
                reinterpret_cast<const unsigned int*>(cp + (yi + ky) * 136 + x0);
            unsigned int a = p[0], b = p[1];
            float f[8] = {(float)(a & 0xff), (float)((a >> 8) & 0xff),
                          (float)((a >> 16) & 0xff), (float)(a >> 24),
                          (float)(b & 0xff), (float)((b >> 8) & 0xff),
                          (float)((b >> 16) & 0xff), (float)(b >> 24)};
            #pragma unroll
            for (int co = 0; co < CH; ++co) {
                const float* wp = w1 + (co * CH + ci) * 25 + ky * 5;
                #pragma unroll
                for (int kx = 0; kx < 5; ++kx) {
                    float wv = wp[kx];
                    #pragma unroll
                    for (int xo = 0; xo < 4; ++xo)
                        acc[co][xo] = fmaf(wv, f[kx + xo], acc[co][xo]);
                }
            }
        }
    }
    __builtin_amdgcn_s_setprio(0);

    float* ob = outp + (size_t)img * CHW + (h0 + yi) * WW + x0;
    #pragma unroll
    for (int co = 0; co < CH; ++co)
        *reinterpret_cast<float4*>(ob + co * HW) =
            make_float4(acc[co][0], acc[co][1], acc[co][2], acc[co][3]);
}

// ---------------------------------------------------------------------------
// K2: fused alpha1 (tau=1) + LIF1 (theta=30, tauRef=1) -> s1 u8.
// ---------------------------------------------------------------------------
__global__ __launch_bounds__(256) void k_alif1(const float* __restrict__ v1,
                                               unsigned char* __restrict__ s1) {
    int e2 = blockIdx.x * blockDim.x + threadIdx.x;   // 0..NCHW/2-1
    if (e2 >= NCHW / 2) return;
    const float d1 = 0.36787944117144233f;  // exp(-1)
    const float c1 = 2.7182818284590452f;   // e
    const float dr = 0.36787944117144233f;  // exp(-1)
    const float rg = 81.54845485377136f;    // 30*e
    const float th = 30.f;
    float P0 = 0.f, Q0 = 0.f, Pr0 = 0.f, Qr0 = 0.f;
    float P1 = 0.f, Q1 = 0.f, Pr1 = 0.f, Qr1 = 0.f;
    const float2* ve = reinterpret_cast<const float2*>(v1);
    #pragma unroll 8
    for (int t = 0; t < TN; ++t) {
        float2 v = ve[(size_t)t * (NCHW / 2) + e2];
        Q0 = d1 * (Q0 + P0); P0 = d1 * P0 + v.x;
        Qr0 = dr * (Qr0 + Pr0);
        float s0 = (c1 * Q0 - rg * Qr0 >= th) ? 1.0f : 0.0f;
        Pr0 = dr * Pr0 + s0;
        Q1 = d1 * (Q1 + P1); P1 = d1 * P1 + v.y;
        Qr1 = dr * (Qr1 + Pr1);
        float s1v = (c1 * Q1 - rg * Qr1 >= th) ? 1.0f : 0.0f;
        Pr1 = dr * Pr1 + s1v;
        uchar2 o; o.x = (unsigned char)s0; o.y = (unsigned char)s1v;
        *reinterpret_cast<uchar2*>(s1 + (size_t)t * NCHW + 2 * e2) = o;
    }
}

// ---------------------------------------------------------------------------
// K3: conv2 3x3 pad=1 on u8 spikes. Same one-barrier u8-tile structure.
// LDS [8][10][136] u8 = 10.9 KB.
// ---------------------------------------------------------------------------
__global__ __launch_bounds__(256, 4) void k_conv2(const unsigned char* __restrict__ in,
                                                  const float* __restrict__ w2,
                                                  float* __restrict__ outp) {
    __shared__ __align__(16) unsigned char lds8[CH * 10 * 136];   // 10880 B
    const int img = blockIdx.y;
    const int h0 = blockIdx.x * 8;
    const int tid = threadIdx.x;
    const int yi = tid >> 5;
    const int x0 = (tid & 31) * 4;
    const unsigned char* base = in + (size_t)img * CHW;

    int goff[6];                                // 10*136 = 1360 slots/channel
    #pragma unroll
    for (int k = 0; k < 6; ++k) {
        int idx = tid + (k << 8);
        int r = idx / 136;
        int c = idx - r * 136;
        int gh = h0 + r - 1, gw = c - 1;
        bool ok = (idx < 1360) && (gh >= 0) && (gh < HH) && (gw >= 0) && (gw < WW);
        goff[k] = ok ? (gh * WW + gw) : -1;
    }

    #pragma unroll
    for (int ci = 0; ci < CH; ++ci) {
        const unsigned char* cb = base + ci * HW;
        #pragma unroll
        for (int k = 0; k < 6; ++k) {
            int idx = tid + (k << 8);
            if (k < 5 || idx < 1360) {
                int g = goff[k];
                int gc = g < 0 ? 0 : g;
                unsigned char v = cb[gc];
                lds8[ci * 1360 + idx] = (g < 0) ? (unsigned char)0 : v;
            }
        }
    }
    __syncthreads();                            // the ONLY barrier

    float acc[CH][4];
    #pragma unroll
    for (int co = 0; co < CH; ++co)
        #pragma unroll
        for (int xo = 0; xo < 4; ++xo) acc[co][xo] = 0.f;

    __builtin_amdgcn_s_setprio(1);              // T5
    for (int ci = 0; ci < CH; ++ci) {
        const unsigned char* cp = lds8 + ci * 1360;
        #pragma unroll
        for (int ky = 0; ky < 3; ++ky) {
            const unsigned int* p =
                reinterpret_cast<const unsigned int*>(cp + (yi + ky) * 136 + x0);
            unsigned int a = p[0], b = p[1];
            float f[8] = {(float)(a & 0xff), (float)((a >> 8) & 0xff),
                          (float)((a >> 16) & 0xff), (float)(a >> 24),
                          (float)(b & 0xff), (float)((b >> 8) & 0xff),
                          (float)((b >> 16) & 0xff), (float)(b >> 24)};
            #pragma unroll
            for (int co = 0; co < CH; ++co) {
                const float* wp = w2 + (co * CH + ci) * 9 + ky * 3;
                #pragma unroll
                for (int kx = 0; kx < 3; ++kx) {
                    float wv = wp[kx];
                    #pragma unroll
                    for (int xo = 0; xo < 4; ++xo)
                        acc[co][xo] = fmaf(wv, f[kx + xo], acc[co][xo]);
                }
            }
        }
    }
    __builtin_amdgcn_s_setprio(0);

    float* ob = outp + (size_t)img * CHW + (h0 + yi) * WW + x0;
    #pragma unroll
    for (int co = 0; co < CH; ++co)
        *reinterpret_cast<float4*>(ob + co * HW) =
            make_float4(acc[co][0], acc[co][1], acc[co][2], acc[co][3]);
}

// ---------------------------------------------------------------------------
// K4: fused alpha2 (tau=2) + LIF2 (theta=50, tauRef=2), t-minor f32 output.
// ---------------------------------------------------------------------------
__global__ __launch_bounds__(256) void k_alif2(const float* __restrict__ v2,
                                               float* __restrict__ outp) {
    int e = blockIdx.x * blockDim.x + threadIdx.x;
    if (e >= NCHW) return;
    const float d2 = 0.60653065971263342f;  // exp(-0.5)
    const float c2 = 1.35914091422952262f;  // e/2
    const float dr = 0.60653065971263342f;  // exp(-0.5)
    const float rg = 67.95704571147613f;    // 25*e
    const float th = 50.f;
    float P = 0.f, Q = 0.f, Pr = 0.f, Qr = 0.f;
    float sv[TN];
    #pragma unroll
    for (int t = 0; t < TN; ++t) {
        Q = d2 * (Q + P);
        P = d2 * P + v2[(size_t)t * NCHW + e];
        Qr = dr * (Qr + Pr);
        float s = (c2 * Q - rg * Qr >= th) ? 1.0f : 0.0f;
        Pr = dr * Pr + s;
        sv[t] = s;
    }
    float4* o = reinterpret_cast<float4*>(outp + (size_t)e * TN);
    #pragma unroll
    for (int i = 0; i < TN / 4; ++i)
        o[i] = make_float4(sv[4 * i], sv[4 * i + 1], sv[4 * i + 2], sv[4 * i + 3]);
}

// ---------------------------------------------------------------------------
extern "C" void kernel_launch(void* const* d_in, const int* in_sizes, int n_in,
                              void* d_out, int out_size, void* d_ws, size_t ws_size,
                              hipStream_t stream) {
    const float* x  = (const float*)d_in[0];   // [2,8,128,128,64] binary
    const float* w1 = (const float*)d_in[1];   // [8,8,5,5]
    const float* w2 = (const float*)d_in[2];   // [8,8,3,3]
    float* out = (float*)d_out;                // [2,8,128,128,64]

    // workspace: v-buffer f32 64MB (v1 then v2) + xT u8 16MB + s1 u8 16MB
    float* vbuf = (float*)d_ws;
    unsigned char* xT = (unsigned char*)d_ws + (size_t)TN * NCHW * 4;
    unsigned char* s1 = xT + (size_t)TN * NCHW;

    dim3 blk(256);
    dim3 grd_pt(NCHW / 256);          // 1024 blocks
    dim3 grd_pt2(NCHW / 512);         // 512 blocks (float2 kernel)
    dim3 grd_cv(16, TN * NB);         // 16 row-tiles x 128 images

    k_tr<<<grd_pt, blk, 0, stream>>>(x, xT);
    k_conv1<<<grd_cv, blk, 0, stream>>>(xT, w1, vbuf);
    k_alif1<<<grd_pt2, blk, 0, stream>>>(vbuf, s1);
    k_conv2<<<grd_cv, blk, 0, stream>>>(s1, w2, vbuf);
    k_alif2<<<grd_pt, blk, 0, stream>>>(vbuf, out);
}

// Round 19
// 178.848 us; speedup vs baseline: 1.2052x; 1.0150x over previous
//
#include <hip/hip_runtime.h>

#define TN 64
#define NB 2
#define CH 8
#define HH 128
#define WW 128
#define HW (HH*WW)        // 16384
#define CHW (CH*HW)       // 131072
#define NCHW (NB*CHW)     // 262144

// ---------------------------------------------------------------------------
// Pipeline (conv∘alpha = alpha∘conv, both linear, disjoint axes):
//   xT = transpose(x) as u8          [t*NB+n][c][h][w]   (x is binary spikes)
//   v1 = conv1(xT)                   f32 t-major
//   s1 = LIF1(alpha1(v1))  as u8
//   v2 = conv2(s1)                   f32 t-major
//   out = LIF2(alpha2(v2))           t-minor [n][c][h][w][t]
//
// Final config (R13): one-barrier u8-tile convs, SMEM weights, hoisted goff.
// Refuted alternatives: co-split (R14), 128-thr blocks (R15), image pairs
// (R16), 8-px strips (R17), s_setprio (R18) — all ≤ this.
// ---------------------------------------------------------------------------

// K0: transpose x [n,c,h,w,t] f32(binary) -> xT [t*NB+n][c][h][w] u8.
__global__ __launch_bounds__(256) void k_tr(const float* __restrict__ x,
                                            unsigned char* __restrict__ xT) {
    __shared__ unsigned char lds[256 * 68];          // [e][68B] pad: 17 words/row
    const int tid = threadIdx.x;
    const size_t e0 = (size_t)blockIdx.x * 256;
    const float4* xb = reinterpret_cast<const float4*>(x + (e0 + tid) * TN);
    unsigned int* lds32 = reinterpret_cast<unsigned int*>(lds);
    #pragma unroll
    for (int k = 0; k < 16; ++k) {
        float4 v = xb[k];
        unsigned int p = ((unsigned)v.x) | (((unsigned)v.y) << 8) |
                         (((unsigned)v.z) << 16) | (((unsigned)v.w) << 24);
        lds32[tid * 17 + k] = p;                     // bank stride 17: conflict-free
    }
    __syncthreads();
    const int lane = tid & 63, w = tid >> 6;
    #pragma unroll
    for (int k = 0; k < 16; ++k) {
        int t = w * 16 + k;
        unsigned int b0 = lds[(4 * lane + 0) * 68 + t];
        unsigned int b1 = lds[(4 * lane + 1) * 68 + t];
        unsigned int b2 = lds[(4 * lane + 2) * 68 + t];
        unsigned int b3 = lds[(4 * lane + 3) * 68 + t];
        unsigned int p = b0 | (b1 << 8) | (b2 << 16) | (b3 << 24);
        *reinterpret_cast<unsigned int*>(xT + (size_t)t * NCHW + e0 + 4 * lane) = p;
    }
}

// ---------------------------------------------------------------------------
// K1: conv1 5x5 pad=2 on u8 input. WHOLE 8-channel tile as u8 in LDS
// ([8][12][136] = 13.1 KB) staged once -> ONE barrier per block; the entire
// 6400-FMA loop then runs sync-free. u8->f32 on read (v_cvt_f32_ubyte).
// Weights via uniform s_load -> SGPR (free FMA operand).
// ---------------------------------------------------------------------------
__global__ __launch_bounds__(256, 4) void k_conv1(const unsigned char* __restrict__ in,
                                                  const float* __restrict__ w1,
                                                  float* __restrict__ outp) {
    __shared__ __align__(16) unsigned char lds8[CH * 12 * 136];   // 13056 B
    const int img = blockIdx.y;                 // t*NB + n, 0..127
    const int h0 = blockIdx.x * 8;              // 16 y-tiles
    const int tid = threadIdx.x;
    const int yi = tid >> 5;                    // 0..7
    const int x0 = (tid & 31) * 4;              // 0..124
    const unsigned char* base = in + (size_t)img * CHW;

    // staging offsets: computed ONCE, reused for all 8 channels
    int goff[7];                                // 12*136 = 1632 slots/channel
    #pragma unroll
    for (int k = 0; k < 7; ++k) {
        int idx = tid + (k << 8);
        int r = idx / 136;
        int c = idx - r * 136;
        int gh = h0 + r - 2, gw = c - 2;
        bool ok = (idx < 1632) && (gh >= 0) && (gh < HH) && (gw >= 0) && (gw < WW);
        goff[k] = ok ? (gh * WW + gw) : -1;
    }

    #pragma unroll
    for (int ci = 0; ci < CH; ++ci) {
        const unsigned char* cb = base + ci * HW;
        #pragma unroll
        for (int k = 0; k < 7; ++k) {
            int idx = tid + (k << 8);
            if (k < 6 || idx < 1632) {
                int g = goff[k];
                int gc = g < 0 ? 0 : g;
                unsigned char v = cb[gc];
                lds8[ci * 1632 + idx] = (g < 0) ? (unsigned char)0 : v;
            }
        }
    }
    __syncthreads();                            // the ONLY barrier

    float acc[CH][4];
    #pragma unroll
    for (int co = 0; co < CH; ++co)
        #pragma unroll
        for (int xo = 0; xo < 4; ++xo) acc[co][xo] = 0.f;

    for (int ci = 0; ci < CH; ++ci) {           // dynamic: keeps code size sane
        const unsigned char* cp = lds8 + ci * 1632;
        #pragma unroll
        for (int ky = 0; ky < 5; ++ky) {
            const unsigned int* p =
                reinterpret_cast<const unsigned int*>(cp + (yi + ky) * 136 + x0);
            unsigned int a = p[0], b = p[1];
            float f[8] = {(float)(a & 0xff), (float)((a >> 8) & 0xff),
                          (float)((a >> 16) & 0xff), (float)(a >> 24),
                          (float)(b & 0xff), (float)((b >> 8) & 0xff),
                          (float)((b >> 16) & 0xff), (float)(b >> 24)};
            #pragma unroll
            for (int co = 0; co < CH; ++co) {
                const float* wp = w1 + (co * CH + ci) * 25 + ky * 5;
                #pragma unroll
                for (int kx = 0; kx < 5; ++kx) {
                    float wv = wp[kx];
                    #pragma unroll
                    for (int xo = 0; xo < 4; ++xo)
                        acc[co][xo] = fmaf(wv, f[kx + xo], acc[co][xo]);
                }
            }
        }
    }

    float* ob = outp + (size_t)img * CHW + (h0 + yi) * WW + x0;
    #pragma unroll
    for (int co = 0; co < CH; ++co)
        *reinterpret_cast<float4*>(ob + co * HW) =
            make_float4(acc[co][0], acc[co][1], acc[co][2], acc[co][3]);
}

// ---------------------------------------------------------------------------
// K2: fused alpha1 (tau=1) + LIF1 (theta=30, tauRef=1) -> s1 u8.
// float2-vectorized (2 IIR chains/thread).
// ---------------------------------------------------------------------------
__global__ __launch_bounds__(256) void k_alif1(const float* __restrict__ v1,
                                               unsigned char* __restrict__ s1) {
    int e2 = blockIdx.x * blockDim.x + threadIdx.x;   // 0..NCHW/2-1
    if (e2 >= NCHW / 2) return;
    const float d1 = 0.36787944117144233f;  // exp(-1)
    const float c1 = 2.7182818284590452f;   // e
    const float dr = 0.36787944117144233f;  // exp(-1)
    const float rg = 81.54845485377136f;    // 30*e
    const float th = 30.f;
    float P0 = 0.f, Q0 = 0.f, Pr0 = 0.f, Qr0 = 0.f;
    float P1 = 0.f, Q1 = 0.f, Pr1 = 0.f, Qr1 = 0.f;
    const float2* ve = reinterpret_cast<const float2*>(v1);
    #pragma unroll 8
    for (int t = 0; t < TN; ++t) {
        float2 v = ve[(size_t)t * (NCHW / 2) + e2];
        Q0 = d1 * (Q0 + P0); P0 = d1 * P0 + v.x;
        Qr0 = dr * (Qr0 + Pr0);
        float s0 = (c1 * Q0 - rg * Qr0 >= th) ? 1.0f : 0.0f;
        Pr0 = dr * Pr0 + s0;
        Q1 = d1 * (Q1 + P1); P1 = d1 * P1 + v.y;
        Qr1 = dr * (Qr1 + Pr1);
        float s1v = (c1 * Q1 - rg * Qr1 >= th) ? 1.0f : 0.0f;
        Pr1 = dr * Pr1 + s1v;
        uchar2 o; o.x = (unsigned char)s0; o.y = (unsigned char)s1v;
        *reinterpret_cast<uchar2*>(s1 + (size_t)t * NCHW + 2 * e2) = o;
    }
}

// ---------------------------------------------------------------------------
// K3: conv2 3x3 pad=1 on u8 spikes. Same one-barrier u8-tile structure.
// LDS [8][10][136] u8 = 10.9 KB.
// ---------------------------------------------------------------------------
__global__ __launch_bounds__(256, 4) void k_conv2(const unsigned char* __restrict__ in,
                                                  const float* __restrict__ w2,
                                                  float* __restrict__ outp) {
    __shared__ __align__(16) unsigned char lds8[CH * 10 * 136];   // 10880 B
    const int img = blockIdx.y;
    const int h0 = blockIdx.x * 8;
    const int tid = threadIdx.x;
    const int yi = tid >> 5;
    const int x0 = (tid & 31) * 4;
    const unsigned char* base = in + (size_t)img * CHW;

    int goff[6];                                // 10*136 = 1360 slots/channel
    #pragma unroll
    for (int k = 0; k < 6; ++k) {
        int idx = tid + (k << 8);
        int r = idx / 136;
        int c = idx - r * 136;
        int gh = h0 + r - 1, gw = c - 1;
        bool ok = (idx < 1360) && (gh >= 0) && (gh < HH) && (gw >= 0) && (gw < WW);
        goff[k] = ok ? (gh * WW + gw) : -1;
    }

    #pragma unroll
    for (int ci = 0; ci < CH; ++ci) {
        const unsigned char* cb = base + ci * HW;
        #pragma unroll
        for (int k = 0; k < 6; ++k) {
            int idx = tid + (k << 8);
            if (k < 5 || idx < 1360) {
                int g = goff[k];
                int gc = g < 0 ? 0 : g;
                unsigned char v = cb[gc];
                lds8[ci * 1360 + idx] = (g < 0) ? (unsigned char)0 : v;
            }
        }
    }
    __syncthreads();                            // the ONLY barrier

    float acc[CH][4];
    #pragma unroll
    for (int co = 0; co < CH; ++co)
        #pragma unroll
        for (int xo = 0; xo < 4; ++xo) acc[co][xo] = 0.f;

    for (int ci = 0; ci < CH; ++ci) {
        const unsigned char* cp = lds8 + ci * 1360;
        #pragma unroll
        for (int ky = 0; ky < 3; ++ky) {
            const unsigned int* p =
                reinterpret_cast<const unsigned int*>(cp + (yi + ky) * 136 + x0);
            unsigned int a = p[0], b = p[1];
            float f[8] = {(float)(a & 0xff), (float)((a >> 8) & 0xff),
                          (float)((a >> 16) & 0xff), (float)(a >> 24),
                          (float)(b & 0xff), (float)((b >> 8) & 0xff),
                          (float)((b >> 16) & 0xff), (float)(b >> 24)};
            #pragma unroll
            for (int co = 0; co < CH; ++co) {
                const float* wp = w2 + (co * CH + ci) * 9 + ky * 3;
                #pragma unroll
                for (int kx = 0; kx < 3; ++kx) {
                    float wv = wp[kx];
                    #pragma unroll
                    for (int xo = 0; xo < 4; ++xo)
                        acc[co][xo] = fmaf(wv, f[kx + xo], acc[co][xo]);
                }
            }
        }
    }

    float* ob = outp + (size_t)img * CHW + (h0 + yi) * WW + x0;
    #pragma unroll
    for (int co = 0; co < CH; ++co)
        *reinterpret_cast<float4*>(ob + co * HW) =
            make_float4(acc[co][0], acc[co][1], acc[co][2], acc[co][3]);
}

// ---------------------------------------------------------------------------
// K4: fused alpha2 (tau=2) + LIF2 (theta=50, tauRef=2), t-minor f32 output.
// ---------------------------------------------------------------------------
__global__ __launch_bounds__(256) void k_alif2(const float* __restrict__ v2,
                                               float* __restrict__ outp) {
    int e = blockIdx.x * blockDim.x + threadIdx.x;
    if (e >= NCHW) return;
    const float d2 = 0.60653065971263342f;  // exp(-0.5)
    const float c2 = 1.35914091422952262f;  // e/2
    const float dr = 0.60653065971263342f;  // exp(-0.5)
    const float rg = 67.95704571147613f;    // 25*e
    const float th = 50.f;
    float P = 0.f, Q = 0.f, Pr = 0.f, Qr = 0.f;
    float sv[TN];
    #pragma unroll
    for (int t = 0; t < TN; ++t) {
        Q = d2 * (Q + P);
        P = d2 * P + v2[(size_t)t * NCHW + e];
        Qr = dr * (Qr + Pr);
        float s = (c2 * Q - rg * Qr >= th) ? 1.0f : 0.0f;
        Pr = dr * Pr + s;
        sv[t] = s;
    }
    float4* o = reinterpret_cast<float4*>(outp + (size_t)e * TN);
    #pragma unroll
    for (int i = 0; i < TN / 4; ++i)
        o[i] = make_float4(sv[4 * i], sv[4 * i + 1], sv[4 * i + 2], sv[4 * i + 3]);
}

// ---------------------------------------------------------------------------
extern "C" void kernel_launch(void* const* d_in, const int* in_sizes, int n_in,
                              void* d_out, int out_size, void* d_ws, size_t ws_size,
                              hipStream_t stream) {
    const float* x  = (const float*)d_in[0];   // [2,8,128,128,64] binary
    const float* w1 = (const float*)d_in[1];   // [8,8,5,5]
    const float* w2 = (const float*)d_in[2];   // [8,8,3,3]
    float* out = (float*)d_out;                // [2,8,128,128,64]

    // workspace: v-buffer f32 64MB (v1 then v2) + xT u8 16MB + s1 u8 16MB
    float* vbuf = (float*)d_ws;
    unsigned char* xT = (unsigned char*)d_ws + (size_t)TN * NCHW * 4;
    unsigned char* s1 = xT + (size_t)TN * NCHW;

    dim3 blk(256);
    dim3 grd_pt(NCHW / 256);          // 1024 blocks
    dim3 grd_pt2(NCHW / 512);         // 512 blocks (float2 kernel)
    dim3 grd_cv(16, TN * NB);         // 16 row-tiles x 128 images

    k_tr<<<grd_pt, blk, 0, stream>>>(x, xT);
    k_conv1<<<grd_cv, blk, 0, stream>>>(xT, w1, vbuf);
    k_alif1<<<grd_pt2, blk, 0, stream>>>(vbuf, s1);
    k_conv2<<<grd_cv, blk, 0, stream>>>(s1, w2, vbuf);
    k_alif2<<<grd_pt, blk, 0, stream>>>(vbuf, out);
}